// Round 16
// baseline (135.108 us; speedup 1.0000x reference)
//
#include <hip/hip_runtime.h>
#include <hip/hip_bf16.h>

typedef unsigned short u16;
typedef __attribute__((ext_vector_type(8))) short short8;
typedef __attribute__((ext_vector_type(4))) float f32x4;
typedef __attribute__((ext_vector_type(16))) float f32x16;

#define MFMA32(a,b,c) __builtin_amdgcn_mfma_f32_32x32x16_bf16(a,b,c,0,0,0)

__device__ __forceinline__ unsigned pk2(float a, float b){
  float2 f = make_float2(a, b);
  __hip_bfloat162 h = __float22bfloat162_rn(f);     // v_cvt_pk_bf16_f32
  unsigned u; __builtin_memcpy(&u, &h, 4); return u;
}

__device__ __forceinline__ short8 pack8(float4 a, float4 b){
  union { unsigned u[4]; short8 s; } v;
  v.u[0] = pk2(a.x, a.y); v.u[1] = pk2(a.z, a.w);
  v.u[2] = pk2(b.x, b.y); v.u[3] = pk2(b.z, b.w);
  return v.s;
}

__device__ __forceinline__ short8 pack8v(f32x4 a, f32x4 b){
  union { unsigned u[4]; short8 s; } v;
  v.u[0] = pk2(a[0], a[1]); v.u[1] = pk2(a[2], a[3]);
  v.u[2] = pk2(b[0], b[1]); v.u[3] = pk2(b[2], b[3]);
  return v.s;
}

__device__ __forceinline__ void gload_lds16(const void* g, void* l){
  __builtin_amdgcn_global_load_lds(
      (const __attribute__((address_space(1))) unsigned int*)g,
      (__attribute__((address_space(3))) unsigned int*)l, 16, 0, 0);
}

// =============== kPrep: W1-permute (B frag chunks) + W2T + GEMM3 ==========
// blocks 0..319: w1bp 16B-slot g: c=g/1280, r=g%1280, nt=r>>7, s=(r>>6)&1,
//   l=r&63; slot holds W1[nt*32+(l&31)][c*32 + s*16 + (l>>5)*8 + j], j=0..7.
__global__ __launch_bounds__(256) void kprep(
    const float* __restrict__ W1, const float* __restrict__ W2,
    const float* __restrict__ feat, const float* __restrict__ W3,
    u16* __restrict__ w1bp, float* __restrict__ W2T, float* __restrict__ l3p)
{
  __shared__ float tile[32][33];
  __shared__ __attribute__((aligned(16))) float At[32*68];
  __shared__ __attribute__((aligned(16))) float Bt[32*68];
  const int bid = blockIdx.x;
  const int t = threadIdx.x;

  if (bid < 320){
    int g = bid * 256 + t;            // 0..81919
    int c = g / 1280;
    int r = g - c * 1280;
    int nt = r >> 7;
    int s = (r >> 6) & 1;
    int l = r & 63;
    int row = nt*32 + (l & 31);
    int k = c*32 + s*16 + (l >> 5)*8;
    const float4* src = (const float4*)(W1 + (size_t)row * 2048 + k);
    *(short8*)(w1bp + (size_t)g * 8) = pack8(src[0], src[1]);
  } else if (bid < 640){
    const int bb = bid - 320;
    const int tx = t & 31, ty = t >> 5;          // 32 x 8
    const int bx = bb & 31;                      // c tile (32 -> 1024)
    const int by = bb >> 5;                      // a tile (10 -> 320)
#pragma unroll
    for (int k = 0; k < 4; ++k){
      int c = bx*32 + ty + k*8;
      int a = by*32 + tx;
      tile[ty + k*8][tx] = (c < 1000) ? W2[(size_t)c*320 + a] : 0.f;
    }
    __syncthreads();
#pragma unroll
    for (int k = 0; k < 4; ++k){
      int a = by*32 + ty + k*8;
      int c = bx*32 + tx;
      W2T[(size_t)a*1024 + c] = tile[tx][ty + k*8];
    }
  } else {
    // ---- GEMM3: 64x64 C tile, K chunk 128 (4 stages of 32) ----
    const int bb = bid - 640;
    const int kg = bb & 15;
    const int cg = bb >> 4;
    const int cbase = cg * 64;
    const int tm = t >> 4, tn = t & 15;
    const int sr = t >> 2, skc = (t & 3) * 8;
    f32x4 acc4[4];
#pragma unroll
    for (int i = 0; i < 4; ++i) acc4[i] = (f32x4){0.f,0.f,0.f,0.f};

    for (int st = 0; st < 4; ++st){
      const int kbase = kg*128 + st*32;
      {
        const float4* s = (const float4*)(feat + (size_t)sr*2048 + kbase + skc);
        float4 v0 = s[0], v1 = s[1];
        At[(skc+0)*68 + sr] = v0.x; At[(skc+1)*68 + sr] = v0.y;
        At[(skc+2)*68 + sr] = v0.z; At[(skc+3)*68 + sr] = v0.w;
        At[(skc+4)*68 + sr] = v1.x; At[(skc+5)*68 + sr] = v1.y;
        At[(skc+6)*68 + sr] = v1.z; At[(skc+7)*68 + sr] = v1.w;
      }
      {
        int c = cbase + sr;
        float4 v0 = {0,0,0,0}, v1 = {0,0,0,0};
        if (c < 1000){
          const float4* s = (const float4*)(W3 + (size_t)c*2048 + kbase + skc);
          v0 = s[0]; v1 = s[1];
        }
        Bt[(skc+0)*68 + sr] = v0.x; Bt[(skc+1)*68 + sr] = v0.y;
        Bt[(skc+2)*68 + sr] = v0.z; Bt[(skc+3)*68 + sr] = v0.w;
        Bt[(skc+4)*68 + sr] = v1.x; Bt[(skc+5)*68 + sr] = v1.y;
        Bt[(skc+6)*68 + sr] = v1.z; Bt[(skc+7)*68 + sr] = v1.w;
      }
      __syncthreads();
#pragma unroll
      for (int kk = 0; kk < 32; ++kk){
        f32x4 a = *(const f32x4*)(At + kk*68 + tm*4);
        f32x4 b = *(const f32x4*)(Bt + kk*68 + tn*4);
        acc4[0] += a[0] * b;
        acc4[1] += a[1] * b;
        acc4[2] += a[2] * b;
        acc4[3] += a[3] * b;
      }
      __syncthreads();
    }
#pragma unroll
    for (int i = 0; i < 4; ++i)
      *(f32x4*)(l3p + (size_t)kg*65536 + (tm*4+i)*1024 + cbase + tn*4) = acc4[i];
  }
}

// =============== K1: GEMM1 (32x32 MFMA) + softmax + region partials =======
// grid 392 (M=32), block 640 = 10 waves; wave wv owns nt=wv (cols wv*32..+32),
// full K; acc = 1 x f32x16 (16 VGPR). All staging via global_load_lds,
// 3-deep (BK=32): per iter per wave 2 B slabs (own) + (wv<4) 1 A load;
// per-wave counted vmcnt + one barrier per chunk. ~76 KB LDS -> 2 blocks/CU.
__global__ __launch_bounds__(640, 2) void k1_main(
    const float* __restrict__ am, const u16* __restrict__ w1bp,
    float* __restrict__ partial)
{
  __shared__ __attribute__((aligned(16))) u16   Bl[3][10240];  // 3 x 20 KB
  __shared__ __attribute__((aligned(16))) float Al[3][1024];   // 3 x 4 KB
  __shared__ float redM[32][10];
  __shared__ float redS[32][10];

  const int t = threadIdx.x;
  const int wv = t >> 6, l = t & 63;
  const int rA = l & 31, hA = l >> 5;
  const int blk = blockIdx.x;

  f32x16 acc;
#pragma unroll
  for (int r = 0; r < 16; ++r) acc[r] = 0.f;

  // B DMA source (per-lane): wave's two slabs per chunk
  const char* bsrc = (const char*)w1bp + (size_t)(2*wv)*1024 + (size_t)l*16;
  // A DMA source (waves 0..3): row wv*8+(l>>3); stored slot p=(l&7) holds
  // global slot p ^ (row&7) ^ ((row>>3)&3)  -> pre-swizzled source
  const float* asrc = am + (size_t)(blk*32 + wv*8 + (l>>3))*2048
                         + (((l&7) ^ (l>>3) ^ (wv&3)) * 4);

  // A ds_read offsets: row rA, slot s=ks*4+hA*2+j stored at s^sw
  const int sw = (rA & 7) ^ ((rA >> 3) & 3);
  const int aof00 = rA*128 + (((0 + hA*2 + 0) ^ sw) * 16);
  const int aof01 = rA*128 + (((0 + hA*2 + 1) ^ sw) * 16);
  const int aof10 = rA*128 + (((4 + hA*2 + 0) ^ sw) * 16);
  const int aof11 = rA*128 + (((4 + hA*2 + 1) ^ sw) * 16);
  const int bq = wv*2048 + l*16;

#define DMAC(KC, BUF)                                                     \
  { gload_lds16(bsrc + (size_t)(KC)*20480,                                \
                (char*)&Bl[BUF][0] + (2*wv)*1024);                        \
    gload_lds16(bsrc + (size_t)(KC)*20480 + 1024,                         \
                (char*)&Bl[BUF][0] + (2*wv+1)*1024);                      \
    if (wv < 4)                                                           \
      gload_lds16(asrc + (size_t)(KC)*32, (char*)&Al[BUF][0] + wv*1024); }

#define CMP(BUF)                                                          \
  { const char* ab = (const char*)&Al[BUF][0];                            \
    const char* bbuf = (const char*)&Bl[BUF][0] + bq;                     \
    f32x4 a0 = *(const f32x4*)(ab + aof00);                               \
    f32x4 a1 = *(const f32x4*)(ab + aof01);                               \
    short8 af0 = pack8v(a0, a1);                                          \
    short8 bf0 = *(const short8*)(bbuf);                                  \
    acc = MFMA32(af0, bf0, acc);                                          \
    f32x4 a2 = *(const f32x4*)(ab + aof10);                               \
    f32x4 a3 = *(const f32x4*)(ab + aof11);                               \
    short8 af1 = pack8v(a2, a3);                                          \
    short8 bf1 = *(const short8*)(bbuf + 1024);                           \
    acc = MFMA32(af1, bf1, acc); }

  // per-wave counted wait (waves 0-3 issue 3/chunk, waves 4-9 issue 2) + barrier
#define WAITB()                                                           \
  { if (wv < 4) asm volatile("s_waitcnt vmcnt(3) lgkmcnt(0)\n\ts_barrier" ::: "memory"); \
    else        asm volatile("s_waitcnt vmcnt(2) lgkmcnt(0)\n\ts_barrier" ::: "memory"); }

  // ---------------- prologue: DMA(0), DMA(1) ----------------
  DMAC(0, 0);
  DMAC(1, 1);
  WAITB();                                    // chunk 0 landed; 1 in flight

  // ---------------- K-loop: 64 chunks (BK=32) ----------------
#pragma unroll 1
  for (int k3 = 0; k3 < 20; ++k3){
    DMAC(3*k3+2, 2); CMP(0); WAITB();
    DMAC(3*k3+3, 0); CMP(1); WAITB();
    DMAC(3*k3+4, 1); CMP(2); WAITB();
  }
  DMAC(62, 2); CMP(0); WAITB();               // k=60
  DMAC(63, 0); CMP(1); WAITB();               // k=61
  CMP(2);                                     // k=62 (chunk 63 in flight)
  asm volatile("s_waitcnt vmcnt(0) lgkmcnt(0)\n\ts_barrier" ::: "memory");
  CMP(0);                                     // k=63

#undef WAITB
#undef CMP
#undef DMAC

  // ---- epilogue: softmax over 320 cols (r10/r11-verified layout) ----
  // C/D: col = wv*32 + (l&31); row = (r&3) + 8*(r>>2) + 4*hA
  {
    float rmx[16];
#pragma unroll
    for (int r = 0; r < 16; ++r){
      float x = acc[r];
      x = fmaxf(x, __shfl_xor(x, 1));
      x = fmaxf(x, __shfl_xor(x, 2));
      x = fmaxf(x, __shfl_xor(x, 4));
      x = fmaxf(x, __shfl_xor(x, 8));
      x = fmaxf(x, __shfl_xor(x, 16));
      rmx[r] = x;
    }
    if ((l & 31) == 0){
#pragma unroll
      for (int r = 0; r < 16; ++r)
        redM[(r&3) + 8*(r>>2) + 4*hA][wv] = rmx[r];
    }
  }
  __syncthreads();
  if (wv == 0 && l < 32){
    float m = redM[l][0];
#pragma unroll
    for (int w2 = 1; w2 < 10; ++w2) m = fmaxf(m, redM[l][w2]);
    redM[l][0] = m;
  }
  __syncthreads();
  {
    float rsum[16];
#pragma unroll
    for (int r = 0; r < 16; ++r){
      int row = (r&3) + 8*(r>>2) + 4*hA;
      float e = __expf(acc[r] - redM[row][0]);
      acc[r] = e;
      float s = e;
      s += __shfl_xor(s, 1);
      s += __shfl_xor(s, 2);
      s += __shfl_xor(s, 4);
      s += __shfl_xor(s, 8);
      s += __shfl_xor(s, 16);
      rsum[r] = s;
    }
    if ((l & 31) == 0){
#pragma unroll
      for (int r = 0; r < 16; ++r)
        redS[(r&3) + 8*(r>>2) + 4*hA][wv] = rsum[r];
    }
  }
  __syncthreads();
  if (wv == 0 && l < 32){
    float s = 0.f;
#pragma unroll
    for (int w2 = 0; w2 < 10; ++w2) s += redS[l][w2];
    redS[l][0] = 1.f / s;
  }
  __syncthreads();
  {
    const int n0 = blk * 32;
    const int thr = 196 * (n0/196 + 1) - n0;   // rows < thr -> seg0
    float s0 = 0.f, s1 = 0.f;
#pragma unroll
    for (int r = 0; r < 16; ++r){
      int row = (r&3) + 8*(r>>2) + 4*hA;
      float v = acc[r] * redS[row][0];
      if (row < thr) s0 += v; else s1 += v;
    }
    s0 += __shfl_xor(s0, 32);
    s1 += __shfl_xor(s1, 32);
    if (l < 32){
      partial[blk*640 +       wv*32 + l] = s0;
      partial[blk*640 + 320 + wv*32 + l] = s1;
    }
  }
}

// =============== K2c: reduce partials + attr_dis@W2T + both softmax =======
__global__ __launch_bounds__(256) void k2c_final(
    const float* __restrict__ partialp, const float* __restrict__ W2T,
    const float* __restrict__ l3p, float* __restrict__ outp,
    float* __restrict__ out_ad)
{
  __shared__ __attribute__((aligned(16))) float sad[320];
  __shared__ float redA[4], redB[4];
  const int b = blockIdx.x, t = threadIdx.x;
  const int w = t >> 6, l = t & 63;
  const int lo = (196*b) >> 5, hi = (196*b + 195) >> 5;
  for (int i = t; i < 320; i += 256){
    float s = 0.f;
    for (int blk = lo; blk <= hi; ++blk){
      int seg = b - (blk*32)/196;
      if (seg >= 0 && seg < 2) s += partialp[blk*640 + seg*320 + i];
    }
    s *= (1.f / 320.f);
    sad[i] = s;
    out_ad[b*320 + i] = s;
  }
  __syncthreads();
  const int c0 = t * 4;
  f32x4 s2v = {0.f,0.f,0.f,0.f};
  const float4* a4 = (const float4*)sad;
#pragma unroll 4
  for (int i = 0; i < 80; ++i){
    float4 sv = a4[i];
    f32x4 w0 = *(const f32x4*)(W2T + (size_t)(4*i  )*1024 + c0);
    f32x4 w1 = *(const f32x4*)(W2T + (size_t)(4*i+1)*1024 + c0);
    f32x4 w2 = *(const f32x4*)(W2T + (size_t)(4*i+2)*1024 + c0);
    f32x4 w3 = *(const f32x4*)(W2T + (size_t)(4*i+3)*1024 + c0);
    s2v += sv.x*w0 + sv.y*w1 + sv.z*w2 + sv.w*w3;
  }
  f32x4 s3v = {0.f,0.f,0.f,0.f};
#pragma unroll
  for (int kg = 0; kg < 16; ++kg)
    s3v += *(const f32x4*)(l3p + (size_t)kg*65536 + b*1024 + c0);
  float l2a[4], l3a[4];
#pragma unroll
  for (int jj = 0; jj < 4; ++jj){
    bool valid = (c0 + jj) < 1000;
    l2a[jj] = valid ? s2v[jj] : -3.4e38f;
    l3a[jj] = valid ? s3v[jj] : -3.4e38f;
  }
  float m2 = fmaxf(fmaxf(l2a[0],l2a[1]), fmaxf(l2a[2],l2a[3]));
  float m3 = fmaxf(fmaxf(l3a[0],l3a[1]), fmaxf(l3a[2],l3a[3]));
#pragma unroll
  for (int off = 32; off > 0; off >>= 1){
    m2 = fmaxf(m2, __shfl_xor(m2, off));
    m3 = fmaxf(m3, __shfl_xor(m3, off));
  }
  if (l == 0){ redA[w] = m2; redB[w] = m3; }
  __syncthreads();
  m2 = fmaxf(fmaxf(redA[0],redA[1]), fmaxf(redA[2],redA[3]));
  m3 = fmaxf(fmaxf(redB[0],redB[1]), fmaxf(redB[2],redB[3]));
  __syncthreads();
  float e2[4], e3[4], s2 = 0.f, s3 = 0.f;
#pragma unroll
  for (int jj = 0; jj < 4; ++jj){
    bool valid = (c0 + jj) < 1000;
    e2[jj] = valid ? __expf(l2a[jj] - m2) : 0.f;
    e3[jj] = valid ? __expf(l3a[jj] - m3) : 0.f;
    s2 += e2[jj]; s3 += e3[jj];
  }
#pragma unroll
  for (int off = 32; off > 0; off >>= 1){
    s2 += __shfl_xor(s2, off);
    s3 += __shfl_xor(s3, off);
  }
  if (l == 0){ redA[w] = s2; redB[w] = s3; }
  __syncthreads();
  s2 = redA[0] + redA[1] + redA[2] + redA[3];
  s3 = redB[0] + redB[1] + redB[2] + redB[3];
  float i2 = 1.f / s2, i3 = 1.f / s3;
#pragma unroll
  for (int jj = 0; jj < 4; ++jj){
    int c = c0 + jj;
    if (c < 1000) outp[b*1000 + c] = 0.5f * (e2[jj]*i2 + e3[jj]*i3);
  }
}

extern "C" void kernel_launch(void* const* d_in, const int* in_sizes, int n_in,
                              void* d_out, int out_size, void* d_ws, size_t ws_size,
                              hipStream_t stream)
{
  const float* attr_map = (const float*)d_in[0];
  const float* features = (const float*)d_in[1];
  const float* W1 = (const float*)d_in[2];
  const float* W2 = (const float*)d_in[3];
  const float* W3 = (const float*)d_in[4];
  float* outp = (float*)d_out;

  char* ws = (char*)d_ws;
  u16*   w1bp    = (u16*)ws;                       // 1,310,720 B
  float* W2T     = (float*)(ws + 1310720);         // 1,310,720 B
  float* partial = (float*)(ws + 2621440);         // 1,003,520 B
  float* l3p     = (float*)(ws + 3624960);         // 4,194,304 B (total 7.8 MB)

  kprep    <<<896, 256, 0, stream>>>(W1, W2, features, W3, w1bp, W2T, l3p);
  k1_main  <<<392, 640, 0, stream>>>(attr_map, w1bp, partial);
  k2c_final<<<64, 256, 0, stream>>>(partial, W2T, l3p, outp, outp + 64000);
}

// Round 17
// 111.585 us; speedup vs baseline: 1.2108x; 1.2108x over previous
//
#include <hip/hip_runtime.h>
#include <hip/hip_bf16.h>

typedef unsigned short u16;
typedef __attribute__((ext_vector_type(8))) short short8;
typedef __attribute__((ext_vector_type(4))) float f32x4;
typedef __attribute__((ext_vector_type(16))) float f32x16;

#define MFMA32(a,b,c) __builtin_amdgcn_mfma_f32_32x32x16_bf16(a,b,c,0,0,0)

__device__ __forceinline__ unsigned pk2(float a, float b){
  float2 f = make_float2(a, b);
  __hip_bfloat162 h = __float22bfloat162_rn(f);     // v_cvt_pk_bf16_f32
  unsigned u; __builtin_memcpy(&u, &h, 4); return u;
}

__device__ __forceinline__ short8 pack8(float4 a, float4 b){
  union { unsigned u[4]; short8 s; } v;
  v.u[0] = pk2(a.x, a.y); v.u[1] = pk2(a.z, a.w);
  v.u[2] = pk2(b.x, b.y); v.u[3] = pk2(b.z, b.w);
  return v.s;
}

// =============== kPrep: W1-permute (32x32 frag order) + W2T + GEMM3 =======
// blocks 0..319: slot gid: cn=gid>>6=kc*10+nt, l=gid&63; holds
//   W1[nt*32+(l&31)][kc*16+(l>>5)*8+j], j=0..7  (verified r10/r11)
__global__ __launch_bounds__(256) void kprep(
    const float* __restrict__ W1, const float* __restrict__ W2,
    const float* __restrict__ feat, const float* __restrict__ W3,
    u16* __restrict__ w1bp, float* __restrict__ W2T, float* __restrict__ l3p)
{
  __shared__ float tile[32][33];
  __shared__ __attribute__((aligned(16))) float At[32*68];
  __shared__ __attribute__((aligned(16))) float Bt[32*68];
  const int bid = blockIdx.x;
  const int t = threadIdx.x;

  if (bid < 320){
    int gid = bid * 256 + t;
    int l = gid & 63;
    int cn = gid >> 6;            // kc*10 + nt
    int kc = cn / 10;
    int nt = cn - kc * 10;
    int row = nt * 32 + (l & 31);
    int col = kc * 16 + (l >> 5) * 8;
    const float4* s = (const float4*)(W1 + (size_t)row * 2048 + col);
    *(short8*)(w1bp + (size_t)gid * 8) = pack8(s[0], s[1]);
  } else if (bid < 640){
    const int bb = bid - 320;
    const int tx = t & 31, ty = t >> 5;          // 32 x 8
    const int bx = bb & 31;                      // c tile (32 -> 1024)
    const int by = bb >> 5;                      // a tile (10 -> 320)
#pragma unroll
    for (int k = 0; k < 4; ++k){
      int c = bx*32 + ty + k*8;
      int a = by*32 + tx;
      tile[ty + k*8][tx] = (c < 1000) ? W2[(size_t)c*320 + a] : 0.f;
    }
    __syncthreads();
#pragma unroll
    for (int k = 0; k < 4; ++k){
      int a = by*32 + ty + k*8;
      int c = bx*32 + tx;
      W2T[(size_t)a*1024 + c] = tile[tx][ty + k*8];
    }
  } else {
    // ---- GEMM3: 64x64 C tile, K chunk 128 (4 stages of 32) ----
    const int bb = bid - 640;
    const int kg = bb & 15;
    const int cg = bb >> 4;
    const int cbase = cg * 64;
    const int tm = t >> 4, tn = t & 15;
    const int sr = t >> 2, skc = (t & 3) * 8;
    f32x4 acc4[4];
#pragma unroll
    for (int i = 0; i < 4; ++i) acc4[i] = (f32x4){0.f,0.f,0.f,0.f};

    for (int st = 0; st < 4; ++st){
      const int kbase = kg*128 + st*32;
      {
        const float4* s = (const float4*)(feat + (size_t)sr*2048 + kbase + skc);
        float4 v0 = s[0], v1 = s[1];
        At[(skc+0)*68 + sr] = v0.x; At[(skc+1)*68 + sr] = v0.y;
        At[(skc+2)*68 + sr] = v0.z; At[(skc+3)*68 + sr] = v0.w;
        At[(skc+4)*68 + sr] = v1.x; At[(skc+5)*68 + sr] = v1.y;
        At[(skc+6)*68 + sr] = v1.z; At[(skc+7)*68 + sr] = v1.w;
      }
      {
        int c = cbase + sr;
        float4 v0 = {0,0,0,0}, v1 = {0,0,0,0};
        if (c < 1000){
          const float4* s = (const float4*)(W3 + (size_t)c*2048 + kbase + skc);
          v0 = s[0]; v1 = s[1];
        }
        Bt[(skc+0)*68 + sr] = v0.x; Bt[(skc+1)*68 + sr] = v0.y;
        Bt[(skc+2)*68 + sr] = v0.z; Bt[(skc+3)*68 + sr] = v0.w;
        Bt[(skc+4)*68 + sr] = v1.x; Bt[(skc+5)*68 + sr] = v1.y;
        Bt[(skc+6)*68 + sr] = v1.z; Bt[(skc+7)*68 + sr] = v1.w;
      }
      __syncthreads();
#pragma unroll
      for (int kk = 0; kk < 32; ++kk){
        f32x4 a = *(const f32x4*)(At + kk*68 + tm*4);
        f32x4 b = *(const f32x4*)(Bt + kk*68 + tn*4);
        acc4[0] += a[0] * b;
        acc4[1] += a[1] * b;
        acc4[2] += a[2] * b;
        acc4[3] += a[3] * b;
      }
      __syncthreads();
    }
#pragma unroll
    for (int i = 0; i < 4; ++i)
      *(f32x4*)(l3p + (size_t)kg*65536 + (tm*4+i)*1024 + cbase + tn*4) = acc4[i];
  }
}

// =============== K1: GEMM1 (32x32 MFMA) + softmax + region partials =======
// grid 392 (M=32), block 640 = 10 waves; wave wv owns cols [wv*32, wv*32+32).
// BK=256 (8 iters, 8 barriers total). A: per-thread 64B-contiguous f32 loads
// (1KB/row/iter HBM bursts) -> cvt_pk -> swizzled LDS dbuf; B: fragment-
// ordered w1bp read per-wave from L2 (1KB coalesced), 16 frags+16 MFMA/iter.
__global__ __launch_bounds__(640) void k1_main(
    const float* __restrict__ am, const u16* __restrict__ w1bp,
    float* __restrict__ partial)
{
  __shared__ __attribute__((aligned(16))) u16 sA[2][8192];   // 2 x 16 KB
  __shared__ float redM[32][10];
  __shared__ float redS[32][10];

  const int t = threadIdx.x;
  const int wv = t >> 6, l = t & 63;
  const int rA = l & 31, hA = l >> 5;
  const int blk = blockIdx.x;
  const char* const w1c = (const char*)w1bp;

  f32x16 acc;
#pragma unroll
  for (int r = 0; r < 16; ++r) acc[r] = 0.f;

  // A staging (threads 0..511): row st_r, 64B span st_c (16 f32)
  const int st_r = t >> 4, st_c = t & 15;
  const float4* gsrc = (const float4*)(am + (size_t)(blk*32 + st_r)*2048 + st_c*16);
  // write slots s0=2*st_c, s1=s0+1, swizzled by row
  const int ws0 = st_r*512 + (((2*st_c    ) ^ (st_r & 7)) << 4);
  const int ws1 = st_r*512 + (((2*st_c + 1) ^ (st_r & 7)) << 4);
  const bool stg = (t < 512);

#define STG_WRITE(BUF, V0, V1, V2, V3)                                  \
  if (stg){                                                             \
    char* d = (char*)&sA[BUF][0];                                       \
    *(short8*)(d + ws0) = pack8(V0, V1);                                \
    *(short8*)(d + ws1) = pack8(V2, V3);                                \
  }

#define CONSUME(IT)                                                      \
  { const char* sAc = ((const char*)&sA[0][0]) + ((IT)&1)*16384;         \
    _Pragma("unroll")                                                    \
    for (int kk = 0; kk < 16; ++kk){                                     \
      short8 af = *(const short8*)(sAc + rA*512 +                        \
                    ((((kk<<1)|hA) ^ (rA & 7)) << 4));                   \
      short8 bf = *(const short8*)(w1c +                                 \
                    (size_t)((((IT)*16 + kk)*10 + wv))*1024 + l*16);     \
      acc = MFMA32(af, bf, acc);                                         \
    } }

  // ---------------- prologue: stage iter 0 ----------------
  {
    float4 v0, v1, v2, v3;
    if (stg){ v0 = gsrc[0]; v1 = gsrc[1]; v2 = gsrc[2]; v3 = gsrc[3]; }
    STG_WRITE(0, v0, v1, v2, v3);
  }
  __syncthreads();

  // ---------------- K-loop: 8 iters of BK=256 ----------------
#pragma unroll 1
  for (int it = 0; it < 8; ++it){
    float4 v0, v1, v2, v3;
    if (it < 7 && stg){
      const float4* g = gsrc + (size_t)(it+1)*64;   // next 256-k slice
      v0 = g[0]; v1 = g[1]; v2 = g[2]; v3 = g[3];
    }
    CONSUME(it);
    if (it < 7){
      STG_WRITE((it+1)&1, v0, v1, v2, v3);
    }
    __syncthreads();
  }

#undef CONSUME
#undef STG_WRITE

  // ---- epilogue: softmax over 320 cols (r10/r16-verified layout) ----
  // C/D: col = wv*32 + (l&31); row = (r&3) + 8*(r>>2) + 4*hA
  {
    float rmx[16];
#pragma unroll
    for (int r = 0; r < 16; ++r){
      float x = acc[r];
      x = fmaxf(x, __shfl_xor(x, 1));
      x = fmaxf(x, __shfl_xor(x, 2));
      x = fmaxf(x, __shfl_xor(x, 4));
      x = fmaxf(x, __shfl_xor(x, 8));
      x = fmaxf(x, __shfl_xor(x, 16));
      rmx[r] = x;
    }
    if ((l & 31) == 0){
#pragma unroll
      for (int r = 0; r < 16; ++r)
        redM[(r&3) + 8*(r>>2) + 4*hA][wv] = rmx[r];
    }
  }
  __syncthreads();
  if (wv == 0 && l < 32){
    float m = redM[l][0];
#pragma unroll
    for (int w2 = 1; w2 < 10; ++w2) m = fmaxf(m, redM[l][w2]);
    redM[l][0] = m;
  }
  __syncthreads();
  {
    float rsum[16];
#pragma unroll
    for (int r = 0; r < 16; ++r){
      int row = (r&3) + 8*(r>>2) + 4*hA;
      float e = __expf(acc[r] - redM[row][0]);
      acc[r] = e;
      float s = e;
      s += __shfl_xor(s, 1);
      s += __shfl_xor(s, 2);
      s += __shfl_xor(s, 4);
      s += __shfl_xor(s, 8);
      s += __shfl_xor(s, 16);
      rsum[r] = s;
    }
    if ((l & 31) == 0){
#pragma unroll
      for (int r = 0; r < 16; ++r)
        redS[(r&3) + 8*(r>>2) + 4*hA][wv] = rsum[r];
    }
  }
  __syncthreads();
  if (wv == 0 && l < 32){
    float s = 0.f;
#pragma unroll
    for (int w2 = 0; w2 < 10; ++w2) s += redS[l][w2];
    redS[l][0] = 1.f / s;
  }
  __syncthreads();
  {
    const int n0 = blk * 32;
    const int thr = 196 * (n0/196 + 1) - n0;   // rows < thr -> seg0
    float s0 = 0.f, s1 = 0.f;
#pragma unroll
    for (int r = 0; r < 16; ++r){
      int row = (r&3) + 8*(r>>2) + 4*hA;
      float v = acc[r] * redS[row][0];
      if (row < thr) s0 += v; else s1 += v;
    }
    s0 += __shfl_xor(s0, 32);
    s1 += __shfl_xor(s1, 32);
    if (l < 32){
      partial[blk*640 +       wv*32 + l] = s0;
      partial[blk*640 + 320 + wv*32 + l] = s1;
    }
  }
}

// =============== K2c: reduce partials + attr_dis@W2T + both softmax =======
__global__ __launch_bounds__(256) void k2c_final(
    const float* __restrict__ partialp, const float* __restrict__ W2T,
    const float* __restrict__ l3p, float* __restrict__ outp,
    float* __restrict__ out_ad)
{
  __shared__ __attribute__((aligned(16))) float sad[320];
  __shared__ float redA[4], redB[4];
  const int b = blockIdx.x, t = threadIdx.x;
  const int w = t >> 6, l = t & 63;
  const int lo = (196*b) >> 5, hi = (196*b + 195) >> 5;
  for (int i = t; i < 320; i += 256){
    float s = 0.f;
    for (int blk = lo; blk <= hi; ++blk){
      int seg = b - (blk*32)/196;
      if (seg >= 0 && seg < 2) s += partialp[blk*640 + seg*320 + i];
    }
    s *= (1.f / 320.f);
    sad[i] = s;
    out_ad[b*320 + i] = s;
  }
  __syncthreads();
  const int c0 = t * 4;
  f32x4 s2v = {0.f,0.f,0.f,0.f};
  const float4* a4 = (const float4*)sad;
#pragma unroll 4
  for (int i = 0; i < 80; ++i){
    float4 sv = a4[i];
    f32x4 w0 = *(const f32x4*)(W2T + (size_t)(4*i  )*1024 + c0);
    f32x4 w1 = *(const f32x4*)(W2T + (size_t)(4*i+1)*1024 + c0);
    f32x4 w2 = *(const f32x4*)(W2T + (size_t)(4*i+2)*1024 + c0);
    f32x4 w3 = *(const f32x4*)(W2T + (size_t)(4*i+3)*1024 + c0);
    s2v += sv.x*w0 + sv.y*w1 + sv.z*w2 + sv.w*w3;
  }
  f32x4 s3v = {0.f,0.f,0.f,0.f};
#pragma unroll
  for (int kg = 0; kg < 16; ++kg)
    s3v += *(const f32x4*)(l3p + (size_t)kg*65536 + b*1024 + c0);
  float l2a[4], l3a[4];
#pragma unroll
  for (int jj = 0; jj < 4; ++jj){
    bool valid = (c0 + jj) < 1000;
    l2a[jj] = valid ? s2v[jj] : -3.4e38f;
    l3a[jj] = valid ? s3v[jj] : -3.4e38f;
  }
  float m2 = fmaxf(fmaxf(l2a[0],l2a[1]), fmaxf(l2a[2],l2a[3]));
  float m3 = fmaxf(fmaxf(l3a[0],l3a[1]), fmaxf(l3a[2],l3a[3]));
#pragma unroll
  for (int off = 32; off > 0; off >>= 1){
    m2 = fmaxf(m2, __shfl_xor(m2, off));
    m3 = fmaxf(m3, __shfl_xor(m3, off));
  }
  if (l == 0){ redA[w] = m2; redB[w] = m3; }
  __syncthreads();
  m2 = fmaxf(fmaxf(redA[0],redA[1]), fmaxf(redA[2],redA[3]));
  m3 = fmaxf(fmaxf(redB[0],redB[1]), fmaxf(redB[2],redB[3]));
  __syncthreads();
  float e2[4], e3[4], s2 = 0.f, s3 = 0.f;
#pragma unroll
  for (int jj = 0; jj < 4; ++jj){
    bool valid = (c0 + jj) < 1000;
    e2[jj] = valid ? __expf(l2a[jj] - m2) : 0.f;
    e3[jj] = valid ? __expf(l3a[jj] - m3) : 0.f;
    s2 += e2[jj]; s3 += e3[jj];
  }
#pragma unroll
  for (int off = 32; off > 0; off >>= 1){
    s2 += __shfl_xor(s2, off);
    s3 += __shfl_xor(s3, off);
  }
  if (l == 0){ redA[w] = s2; redB[w] = s3; }
  __syncthreads();
  s2 = redA[0] + redA[1] + redA[2] + redA[3];
  s3 = redB[0] + redB[1] + redB[2] + redB[3];
  float i2 = 1.f / s2, i3 = 1.f / s3;
#pragma unroll
  for (int jj = 0; jj < 4; ++jj){
    int c = c0 + jj;
    if (c < 1000) outp[b*1000 + c] = 0.5f * (e2[jj]*i2 + e3[jj]*i3);
  }
}

extern "C" void kernel_launch(void* const* d_in, const int* in_sizes, int n_in,
                              void* d_out, int out_size, void* d_ws, size_t ws_size,
                              hipStream_t stream)
{
  const float* attr_map = (const float*)d_in[0];
  const float* features = (const float*)d_in[1];
  const float* W1 = (const float*)d_in[2];
  const float* W2 = (const float*)d_in[3];
  const float* W3 = (const float*)d_in[4];
  float* outp = (float*)d_out;

  char* ws = (char*)d_ws;
  u16*   w1bp    = (u16*)ws;                       // 1,310,720 B
  float* W2T     = (float*)(ws + 1310720);         // 1,310,720 B
  float* partial = (float*)(ws + 2621440);         // 1,003,520 B
  float* l3p     = (float*)(ws + 3624960);         // 4,194,304 B (total 7.8 MB)

  kprep    <<<896, 256, 0, stream>>>(W1, W2, features, W3, w1bp, W2T, l3p);
  k1_main  <<<392, 640, 0, stream>>>(attr_map, w1bp, partial);
  k2c_final<<<64, 256, 0, stream>>>(partial, W2T, l3p, outp, outp + 64000);
}